// Round 5
// baseline (461.611 us; speedup 1.0000x reference)
//
#include <hip/hip_runtime.h>

typedef _Float16 f16;
typedef f16 f16x8 __attribute__((ext_vector_type(8)));
typedef f16 f16x4 __attribute__((ext_vector_type(4)));
typedef float f32x4 __attribute__((ext_vector_type(4)));

#define QLEN 2048
#define BSZ 2
#define NH 16
#define DH 64
#define DM 1024
#define NBN (BSZ*NH)
#define SCALE 0.125f

static __device__ __forceinline__ f32x4 mfma16(f16x8 a, f16x8 b, f32x4 c) {
  return __builtin_amdgcn_mfma_f32_16x16x32_f16(a, b, c, 0, 0, 0);
}

// async global->LDS, 16B per lane; lds dest = wave-uniform base + lane*16
static __device__ __forceinline__ void gload_lds16(const void* g, void* l) {
  __builtin_amdgcn_global_load_lds((const __attribute__((address_space(1))) unsigned int*)g,
                                   (__attribute__((address_space(3))) unsigned int*)l,
                                   16, 0, 0);
}

// ---------------- K0a: fp32 -> fp16 convert ----------------
__global__ __launch_bounds__(256) void cvt_f32_f16(const float* __restrict__ s,
                                                   f16* __restrict__ d, int n4) {
  int idx = blockIdx.x * 256 + threadIdx.x;
  if (idx >= n4) return;
  f32x4 v = ((const f32x4*)s)[idx];
  f16x4 o;
#pragma unroll
  for (int q = 0; q < 4; ++q) o[q] = (f16)v[q];
  ((f16x4*)d)[idx] = o;
}

// ---------------- K0b: QKV GEMM  C[r][c] = sum_k hh[r][k]*wh[c][k] ----------
__global__ __launch_bounds__(256) void qkv_gemm(const f16* __restrict__ A, const f16* __restrict__ W,
                                                f16* __restrict__ Qs, f16* __restrict__ Ks,
                                                f16* __restrict__ Vt) {
  __shared__ f16 As[128 * 32];
  __shared__ f16 Bs[128 * 32];
  const int bid = blockIdx.x;
  const int r0 = (bid & 31) << 7;
  const int c0 = (bid >> 5) << 7;
  const int t = threadIdx.x;
  const int lane = t & 63, w = t >> 6;
  const int wr = (w >> 1) << 6, wc = (w & 1) << 6;
  const int l15 = lane & 15, lhi = lane >> 4;

  f32x4 acc[4][4] = {};

  const f16* ga = A + (size_t)(r0 + (t >> 2)) * DM + ((t & 3) << 3);
  const f16* gb = W + (size_t)(c0 + (t >> 2)) * DM + ((t & 3) << 3);
  char* la = (char*)As + w * 1024;
  char* lb = (char*)Bs + w * 1024;

  for (int k0 = 0; k0 < DM; k0 += 32) {
    __syncthreads();
    gload_lds16(ga + k0, la);
    gload_lds16(ga + k0 + (size_t)64 * DM, la + 4096);
    gload_lds16(gb + k0, lb);
    gload_lds16(gb + k0 + (size_t)64 * DM, lb + 4096);
    __syncthreads();
    f16x8 af[4], bf[4];
#pragma unroll
    for (int m = 0; m < 4; ++m)
      af[m] = *(const f16x8*)&As[(wr + m * 16 + l15) * 32 + lhi * 8];
#pragma unroll
    for (int n = 0; n < 4; ++n)
      bf[n] = *(const f16x8*)&Bs[(wc + n * 16 + l15) * 32 + lhi * 8];
#pragma unroll
    for (int m = 0; m < 4; ++m)
#pragma unroll
      for (int n = 0; n < 4; ++n)
        acc[m][n] = mfma16(af[m], bf[n], acc[m][n]);
  }

  const int part = c0 >> 10;  // uniform per block
#pragma unroll
  for (int m = 0; m < 4; ++m) {
#pragma unroll
    for (int n = 0; n < 4; ++n) {
#pragma unroll
      for (int q = 0; q < 4; ++q) {
        int r = r0 + wr + m * 16 + lhi * 4 + q;
        int c = c0 + wc + n * 16 + l15;
        int i = r >> 1, b = r & 1;
        int nh = (c >> 6) & 15, d = c & 63;
        int bn = b * 16 + nh;
        f16 v = (f16)acc[m][n][q];
        if (part == 0)       Qs[((size_t)bn * QLEN + i) * DH + d] = v;
        else if (part == 1)  Ks[((size_t)bn * QLEN + i) * DH + d] = v;
        else                 Vt[((size_t)bn * DH + d) * QLEN + i] = v;
      }
    }
  }
}

// ---------------- K1: flash attention -> attn_vec + row stats ----------------
__global__ __launch_bounds__(256) void flash_attn(const f16* __restrict__ Qs, const f16* __restrict__ Ks,
                                                  const f16* __restrict__ Vt, float* __restrict__ av,
                                                  float* __restrict__ sm, float* __restrict__ srl) {
  __shared__ f16 plds[4][16 * 32];
  const int bid = blockIdx.x;
  const int bn = bid >> 4, ib = bid & 15;
  const int t = threadIdx.x, lane = t & 63, w = t >> 6;
  const int l15 = lane & 15, lhi = lane >> 4;
  const int i0 = (ib << 7) + (w << 5);
  const f16* Qb = Qs + ((size_t)bn << 17);
  const f16* Kb = Ks + ((size_t)bn << 17);
  const f16* Vb = Vt + ((size_t)bn << 17);
  f16* pw = plds[w];

  f16x8 qf[2][2];
#pragma unroll
  for (int rg = 0; rg < 2; ++rg)
#pragma unroll
    for (int kc = 0; kc < 2; ++kc)
      qf[rg][kc] = *(const f16x8*)&Qb[(size_t)(i0 + rg * 16 + l15) * DH + kc * 32 + lhi * 8];

  f32x4 o[2][4] = {};
  float mrun[2][4], lrun[2][4];
#pragma unroll
  for (int rg = 0; rg < 2; ++rg)
#pragma unroll
    for (int q = 0; q < 4; ++q) { mrun[rg][q] = -1e30f; lrun[rg][q] = 0.f; }

  for (int j0 = 0; j0 < QLEN; j0 += 32) {
    f16x8 kf[2][2], vf[4];
#pragma unroll
    for (int jc = 0; jc < 2; ++jc)
#pragma unroll
      for (int kc = 0; kc < 2; ++kc)
        kf[jc][kc] = *(const f16x8*)&Kb[(size_t)(j0 + jc * 16 + l15) * DH + kc * 32 + lhi * 8];
#pragma unroll
    for (int dc = 0; dc < 4; ++dc)
      vf[dc] = *(const f16x8*)&Vb[(size_t)(dc * 16 + l15) * QLEN + j0 + lhi * 8];

#pragma unroll
    for (int rg = 0; rg < 2; ++rg) {
      f32x4 s[2];
#pragma unroll
      for (int jc = 0; jc < 2; ++jc) {
        f32x4 z = {0.f, 0.f, 0.f, 0.f};
        z = mfma16(qf[rg][0], kf[jc][0], z);
        z = mfma16(qf[rg][1], kf[jc][1], z);
        s[jc] = z;
      }
      float p[2][4], alpha[4];
#pragma unroll
      for (int q = 0; q < 4; ++q) {
        float v0 = s[0][q] * SCALE, v1 = s[1][q] * SCALE;
        float tm = fmaxf(v0, v1);
        tm = fmaxf(tm, __shfl_xor(tm, 1));
        tm = fmaxf(tm, __shfl_xor(tm, 2));
        tm = fmaxf(tm, __shfl_xor(tm, 4));
        tm = fmaxf(tm, __shfl_xor(tm, 8));
        float mnew = fmaxf(mrun[rg][q], tm);
        alpha[q] = __expf(mrun[rg][q] - mnew);
        mrun[rg][q] = mnew;
        p[0][q] = __expf(v0 - mnew);
        p[1][q] = __expf(v1 - mnew);
        float r = p[0][q] + p[1][q];
        r += __shfl_xor(r, 1);
        r += __shfl_xor(r, 2);
        r += __shfl_xor(r, 4);
        r += __shfl_xor(r, 8);
        lrun[rg][q] = lrun[rg][q] * alpha[q] + r;
      }
#pragma unroll
      for (int dc = 0; dc < 4; ++dc)
#pragma unroll
        for (int q = 0; q < 4; ++q)
          o[rg][dc][q] *= alpha[q];
#pragma unroll
      for (int jc = 0; jc < 2; ++jc)
#pragma unroll
        for (int q = 0; q < 4; ++q)
          pw[(lhi * 4 + q) * 32 + jc * 16 + l15] = (f16)p[jc][q];
      f16x8 pa = *(const f16x8*)&pw[l15 * 32 + lhi * 8];
#pragma unroll
      for (int dc = 0; dc < 4; ++dc)
        o[rg][dc] = mfma16(pa, vf[dc], o[rg][dc]);
    }
  }

  const int b = bn >> 4, nh = bn & 15;
#pragma unroll
  for (int rg = 0; rg < 2; ++rg)
#pragma unroll
    for (int dc = 0; dc < 4; ++dc)
#pragma unroll
      for (int q = 0; q < 4; ++q) {
        int i = i0 + rg * 16 + lhi * 4 + q;
        av[((size_t)i * BSZ + b) * (NH * DH) + nh * DH + dc * 16 + l15] =
            o[rg][dc][q] / lrun[rg][q];
      }
  if (l15 == 0) {
#pragma unroll
    for (int rg = 0; rg < 2; ++rg)
#pragma unroll
      for (int q = 0; q < 4; ++q) {
        int i = i0 + rg * 16 + lhi * 4 + q;
        sm[bn * QLEN + i] = mrun[rg][q];
        srl[bn * QLEN + i] = 1.0f / lrun[rg][q];
      }
  }
}

// ---------------- K2: materialize attn_prob [i][j][b][n] ----------------
// R5: 16i x 16j x 32bn tile = 32 KiB LDS -> 4 blocks/CU (launch_bounds 256,4)
// so compute phases hide under other blocks' store phases. Whole-128B-line
// stores preserved: each store instruction = 4KB contiguous (2 i-rows x 2KB).
// nt stores restored (measured better in R3 vs R4).
__global__ __launch_bounds__(256, 4) void write_probs(const f16* __restrict__ Qs, const f16* __restrict__ Ks,
                                                      const float* __restrict__ sm, const float* __restrict__ srl,
                                                      float* __restrict__ pout) {
  __shared__ float tile[16 * 16 * 32];  // [i][j][8 quads swizzled][4] = 32 KiB
  const int bid = blockIdx.x;
  const int it = bid >> 7, jt = bid & 127;  // 128 x 128 tiles; jt%8 -> XCD-local K
  const int i0 = it << 4, j0 = jt << 4;
  const int t = threadIdx.x, lane = t & 63, w = t >> 6;
  const int l15 = lane & 15, lhi = lane >> 4;
  float st[8][4];

#pragma unroll
  for (int bl = 0; bl < 8; ++bl) {
    const int bn = w * 8 + bl;
    const f16* Qb = Qs + ((size_t)bn << 17);
    const f16* Kb = Ks + ((size_t)bn << 17);
    f16x8 qf[2], kf[2];
#pragma unroll
    for (int kc = 0; kc < 2; ++kc) {
      qf[kc] = *(const f16x8*)&Qb[(size_t)(i0 + l15) * DH + kc * 32 + lhi * 8];
      kf[kc] = *(const f16x8*)&Kb[(size_t)(j0 + l15) * DH + kc * 32 + lhi * 8];
    }
    f32x4 z = {0.f, 0.f, 0.f, 0.f};
    z = mfma16(qf[0], kf[0], z);
    z = mfma16(qf[1], kf[1], z);
    float mm[4], rl[4];
#pragma unroll
    for (int q = 0; q < 4; ++q) {
      int i = i0 + lhi * 4 + q;
      mm[q] = sm[bn * QLEN + i];
      rl[q] = srl[bn * QLEN + i];
    }
#pragma unroll
    for (int q = 0; q < 4; ++q)
      st[bl][q] = __expf(z[q] * SCALE - mm[q]) * rl[q];
  }

  // deposit: 8 x ds_write_b128 per thread; quad swizzle swq = (bn>>2)^(j&7)
#pragma unroll
  for (int q = 0; q < 4; ++q) {
    const int i_l = lhi * 4 + q;
    const int j_l = l15;
    const int base = (i_l * 16 + j_l) * 32;
#pragma unroll
    for (int h = 0; h < 2; ++h) {
      const int g4 = w * 2 + h;            // = bn>>2
      const int swq = g4 ^ (j_l & 7);
      f32x4 v = {st[4 * h + 0][q], st[4 * h + 1][q],
                 st[4 * h + 2][q], st[4 * h + 3][q]};
      *(f32x4*)&tile[base + (swq << 2)] = v;
    }
  }
  __syncthreads();

  // cooperative store: 8 instructions/thread, each = 4KB contiguous
  // (256 lanes x 16B covering 2 i-rows of 16j x 32bn)
  const int bq = t & 7;              // bn quad 0..7
  const int j_r = (t >> 3) & 15;     // 0..15
  const int rh = t >> 7;             // row half 0/1
  const int swr = bq ^ (j_r & 7);
  float* obase = pout + ((size_t)(i0 + rh) * QLEN + j0 + j_r) * NBN + bq * 4;
#pragma unroll
  for (int r = 0; r < 8; ++r) {
    const int row = r * 2 + rh;
    f32x4 v = *(const f32x4*)&tile[(row * 16 + j_r) * 32 + (swr << 2)];
    __builtin_nontemporal_store(v, (f32x4*)(obase + (size_t)r * 2 * QLEN * NBN));
  }
}

// ---------------- launcher ----------------
extern "C" void kernel_launch(void* const* d_in, const int* in_sizes, int n_in,
                              void* d_out, int out_size, void* d_ws, size_t ws_size,
                              hipStream_t stream) {
  const float* h  = (const float*)d_in[0];
  const float* wq = (const float*)d_in[1];
  float* av   = (float*)d_out;
  float* pout = av + (size_t)QLEN * BSZ * NH * DH;

  char* ws = (char*)d_ws;
  f16* hh  = (f16*)ws;                        // 8 MiB
  f16* wh  = (f16*)(ws + (8u << 20));         // 6 MiB
  f16* Qsc = (f16*)(ws + (16u << 20));        // 8 MiB
  f16* Ksc = (f16*)(ws + (24u << 20));        // 8 MiB
  f16* Vtc = (f16*)(ws + (32u << 20));        // 8 MiB
  float* smv  = (float*)(ws + (40u << 20));
  float* srlv = (float*)(ws + (40u << 20) + (QLEN * NBN * 4));

  const int nh4 = QLEN * BSZ * DM / 4;
  const int nw4 = 3 * NH * DH * DM / 4;
  cvt_f32_f16<<<nh4 / 256, 256, 0, stream>>>(h, hh, nh4);
  cvt_f32_f16<<<nw4 / 256, 256, 0, stream>>>(wq, wh, nw4);
  qkv_gemm<<<32 * 24, 256, 0, stream>>>(hh, wh, Qsc, Ksc, Vtc);
  flash_attn<<<NBN * 16, 256, 0, stream>>>(Qsc, Ksc, Vtc, av, smv, srlv);
  write_probs<<<128 * 128, 256, 0, stream>>>(Qsc, Ksc, smv, srlv, pout);
}

// Round 6
// 378.798 us; speedup vs baseline: 1.2186x; 1.2186x over previous
//
#include <hip/hip_runtime.h>

typedef _Float16 f16;
typedef f16 f16x8 __attribute__((ext_vector_type(8)));
typedef f16 f16x4 __attribute__((ext_vector_type(4)));
typedef float f32x4 __attribute__((ext_vector_type(4)));

#define QLEN 2048
#define BSZ 2
#define NH 16
#define DH 64
#define DM 1024
#define NBN (BSZ*NH)
#define SCALE 0.125f

static __device__ __forceinline__ f32x4 mfma16(f16x8 a, f16x8 b, f32x4 c) {
  return __builtin_amdgcn_mfma_f32_16x16x32_f16(a, b, c, 0, 0, 0);
}

// async global->LDS, 16B per lane; lds dest = wave-uniform base + lane*16
static __device__ __forceinline__ void gload_lds16(const void* g, void* l) {
  __builtin_amdgcn_global_load_lds((const __attribute__((address_space(1))) unsigned int*)g,
                                   (__attribute__((address_space(3))) unsigned int*)l,
                                   16, 0, 0);
}

// ---------------- K0a: fp32 -> fp16 convert ----------------
__global__ __launch_bounds__(256) void cvt_f32_f16(const float* __restrict__ s,
                                                   f16* __restrict__ d, int n4) {
  int idx = blockIdx.x * 256 + threadIdx.x;
  if (idx >= n4) return;
  f32x4 v = ((const f32x4*)s)[idx];
  f16x4 o;
#pragma unroll
  for (int q = 0; q < 4; ++q) o[q] = (f16)v[q];
  ((f16x4*)d)[idx] = o;
}

// ---------------- K0b: QKV GEMM  C[r][c] = sum_k hh[r][k]*wh[c][k] ----------
__global__ __launch_bounds__(256) void qkv_gemm(const f16* __restrict__ A, const f16* __restrict__ W,
                                                f16* __restrict__ Qs, f16* __restrict__ Ks,
                                                f16* __restrict__ Vt) {
  __shared__ f16 As[128 * 32];
  __shared__ f16 Bs[128 * 32];
  const int bid = blockIdx.x;
  const int r0 = (bid & 31) << 7;
  const int c0 = (bid >> 5) << 7;
  const int t = threadIdx.x;
  const int lane = t & 63, w = t >> 6;
  const int wr = (w >> 1) << 6, wc = (w & 1) << 6;
  const int l15 = lane & 15, lhi = lane >> 4;

  f32x4 acc[4][4] = {};

  const f16* ga = A + (size_t)(r0 + (t >> 2)) * DM + ((t & 3) << 3);
  const f16* gb = W + (size_t)(c0 + (t >> 2)) * DM + ((t & 3) << 3);
  char* la = (char*)As + w * 1024;
  char* lb = (char*)Bs + w * 1024;

  for (int k0 = 0; k0 < DM; k0 += 32) {
    __syncthreads();
    gload_lds16(ga + k0, la);
    gload_lds16(ga + k0 + (size_t)64 * DM, la + 4096);
    gload_lds16(gb + k0, lb);
    gload_lds16(gb + k0 + (size_t)64 * DM, lb + 4096);
    __syncthreads();
    f16x8 af[4], bf[4];
#pragma unroll
    for (int m = 0; m < 4; ++m)
      af[m] = *(const f16x8*)&As[(wr + m * 16 + l15) * 32 + lhi * 8];
#pragma unroll
    for (int n = 0; n < 4; ++n)
      bf[n] = *(const f16x8*)&Bs[(wc + n * 16 + l15) * 32 + lhi * 8];
#pragma unroll
    for (int m = 0; m < 4; ++m)
#pragma unroll
      for (int n = 0; n < 4; ++n)
        acc[m][n] = mfma16(af[m], bf[n], acc[m][n]);
  }

  const int part = c0 >> 10;  // uniform per block
#pragma unroll
  for (int m = 0; m < 4; ++m) {
#pragma unroll
    for (int n = 0; n < 4; ++n) {
#pragma unroll
      for (int q = 0; q < 4; ++q) {
        int r = r0 + wr + m * 16 + lhi * 4 + q;
        int c = c0 + wc + n * 16 + l15;
        int i = r >> 1, b = r & 1;
        int nh = (c >> 6) & 15, d = c & 63;
        int bn = b * 16 + nh;
        f16 v = (f16)acc[m][n][q];
        if (part == 0)       Qs[((size_t)bn * QLEN + i) * DH + d] = v;
        else if (part == 1)  Ks[((size_t)bn * QLEN + i) * DH + d] = v;
        else                 Vt[((size_t)bn * DH + d) * QLEN + i] = v;
      }
    }
  }
}

// ---------------- K1: flash attention -> attn_vec + row stats ----------------
__global__ __launch_bounds__(256) void flash_attn(const f16* __restrict__ Qs, const f16* __restrict__ Ks,
                                                  const f16* __restrict__ Vt, float* __restrict__ av,
                                                  float* __restrict__ sm, float* __restrict__ srl) {
  __shared__ f16 plds[4][16 * 32];
  const int bid = blockIdx.x;
  const int bn = bid >> 4, ib = bid & 15;
  const int t = threadIdx.x, lane = t & 63, w = t >> 6;
  const int l15 = lane & 15, lhi = lane >> 4;
  const int i0 = (ib << 7) + (w << 5);
  const f16* Qb = Qs + ((size_t)bn << 17);
  const f16* Kb = Ks + ((size_t)bn << 17);
  const f16* Vb = Vt + ((size_t)bn << 17);
  f16* pw = plds[w];

  f16x8 qf[2][2];
#pragma unroll
  for (int rg = 0; rg < 2; ++rg)
#pragma unroll
    for (int kc = 0; kc < 2; ++kc)
      qf[rg][kc] = *(const f16x8*)&Qb[(size_t)(i0 + rg * 16 + l15) * DH + kc * 32 + lhi * 8];

  f32x4 o[2][4] = {};
  float mrun[2][4], lrun[2][4];
#pragma unroll
  for (int rg = 0; rg < 2; ++rg)
#pragma unroll
    for (int q = 0; q < 4; ++q) { mrun[rg][q] = -1e30f; lrun[rg][q] = 0.f; }

  for (int j0 = 0; j0 < QLEN; j0 += 32) {
    f16x8 kf[2][2], vf[4];
#pragma unroll
    for (int jc = 0; jc < 2; ++jc)
#pragma unroll
      for (int kc = 0; kc < 2; ++kc)
        kf[jc][kc] = *(const f16x8*)&Kb[(size_t)(j0 + jc * 16 + l15) * DH + kc * 32 + lhi * 8];
#pragma unroll
    for (int dc = 0; dc < 4; ++dc)
      vf[dc] = *(const f16x8*)&Vb[(size_t)(dc * 16 + l15) * QLEN + j0 + lhi * 8];

#pragma unroll
    for (int rg = 0; rg < 2; ++rg) {
      f32x4 s[2];
#pragma unroll
      for (int jc = 0; jc < 2; ++jc) {
        f32x4 z = {0.f, 0.f, 0.f, 0.f};
        z = mfma16(qf[rg][0], kf[jc][0], z);
        z = mfma16(qf[rg][1], kf[jc][1], z);
        s[jc] = z;
      }
      float p[2][4], alpha[4];
#pragma unroll
      for (int q = 0; q < 4; ++q) {
        float v0 = s[0][q] * SCALE, v1 = s[1][q] * SCALE;
        float tm = fmaxf(v0, v1);
        tm = fmaxf(tm, __shfl_xor(tm, 1));
        tm = fmaxf(tm, __shfl_xor(tm, 2));
        tm = fmaxf(tm, __shfl_xor(tm, 4));
        tm = fmaxf(tm, __shfl_xor(tm, 8));
        float mnew = fmaxf(mrun[rg][q], tm);
        alpha[q] = __expf(mrun[rg][q] - mnew);
        mrun[rg][q] = mnew;
        p[0][q] = __expf(v0 - mnew);
        p[1][q] = __expf(v1 - mnew);
        float r = p[0][q] + p[1][q];
        r += __shfl_xor(r, 1);
        r += __shfl_xor(r, 2);
        r += __shfl_xor(r, 4);
        r += __shfl_xor(r, 8);
        lrun[rg][q] = lrun[rg][q] * alpha[q] + r;
      }
#pragma unroll
      for (int dc = 0; dc < 4; ++dc)
#pragma unroll
        for (int q = 0; q < 4; ++q)
          o[rg][dc][q] *= alpha[q];
#pragma unroll
      for (int jc = 0; jc < 2; ++jc)
#pragma unroll
        for (int q = 0; q < 4; ++q)
          pw[(lhi * 4 + q) * 32 + jc * 16 + l15] = (f16)p[jc][q];
      f16x8 pa = *(const f16x8*)&pw[l15 * 32 + lhi * 8];
#pragma unroll
      for (int dc = 0; dc < 4; ++dc)
        o[rg][dc] = mfma16(pa, vf[dc], o[rg][dc]);
    }
  }

  const int b = bn >> 4, nh = bn & 15;
#pragma unroll
  for (int rg = 0; rg < 2; ++rg)
#pragma unroll
    for (int dc = 0; dc < 4; ++dc)
#pragma unroll
      for (int q = 0; q < 4; ++q) {
        int i = i0 + rg * 16 + lhi * 4 + q;
        av[((size_t)i * BSZ + b) * (NH * DH) + nh * DH + dc * 16 + l15] =
            o[rg][dc][q] / lrun[rg][q];
      }
  if (l15 == 0) {
#pragma unroll
    for (int rg = 0; rg < 2; ++rg)
#pragma unroll
      for (int q = 0; q < 4; ++q) {
        int i = i0 + rg * 16 + lhi * 4 + q;
        sm[bn * QLEN + i] = mrun[rg][q];
        srl[bn * QLEN + i] = 1.0f / lrun[rg][q];
      }
  }
}

// ---------------- K2: materialize attn_prob [i][j][b][n] ----------------
// R6: fabric-traffic-minimizing tiles. TI=16, TJ=256 -> Q re-read traffic
// drops 537MB -> 64MB (Q per block re-read per chunk stays L1/L2-warm;
// K panels 1MB/XCD L2-resident). Per block: 8 j-chunks of 32; each of 4
// waves computes its 8 bn, deposits f16 probs into a 32KB LDS tile
// (granule-XOR swizzle), one barrier, cooperative whole-128B-line nt
// stores. Double-buffered tiles: stores of chunk c drain under compute
// of chunk c+1. 2 blocks/CU.
__global__ __launch_bounds__(256, 2) void write_probs(const f16* __restrict__ Qs, const f16* __restrict__ Ks,
                                                      const float* __restrict__ sm, const float* __restrict__ srl,
                                                      float* __restrict__ pout) {
  __shared__ f16 tile[2][16 * 32 * 32];  // 2 x 32 KiB
  const int bid = blockIdx.x;            // 1024 blocks
  const int it = bid >> 3, jt = bid & 7; // jt%8 -> XCD-local K panel
  const int i0 = it << 4, j0 = jt << 8;
  const int t = threadIdx.x, lane = t & 63, w = t >> 6;
  const int l15 = lane & 15, lhi = lane >> 4;

  // persistent row stats for this wave's 8 bn (broadcast loads)
  float mm[8][4], rl[8][4];
#pragma unroll
  for (int bl = 0; bl < 8; ++bl) {
    const int bn = w * 8 + bl;
#pragma unroll
    for (int q = 0; q < 4; ++q) {
      const int i = i0 + lhi * 4 + q;
      mm[bl][q] = sm[bn * QLEN + i];
      rl[bl][q] = srl[bn * QLEN + i];
    }
  }

  // store-phase lane mapping (constant across chunks)
  const int o = t & 3;             // bn octet 0..3
  const int jl_s = (t >> 2) & 31;  // j within chunk
  const int ihalf = t >> 7;        // i parity
  const int quad = o ^ ((jl_s & 7) >> 1);
  const bool hsw = (jl_s & 1);

  for (int ch = 0; ch < 8; ++ch) {
    f16* tb = tile[ch & 1];
    const int jbase = j0 + ch * 32;

    f16 stv[8][2][4];
#pragma unroll
    for (int bl = 0; bl < 8; ++bl) {
      const int bn = w * 8 + bl;
      const f16* Qb = Qs + ((size_t)bn << 17);
      const f16* Kb = Ks + ((size_t)bn << 17);
      f16x8 qf[2], kf[2][2];
#pragma unroll
      for (int kc = 0; kc < 2; ++kc)
        qf[kc] = *(const f16x8*)&Qb[(size_t)(i0 + l15) * DH + kc * 32 + lhi * 8];
#pragma unroll
      for (int jc = 0; jc < 2; ++jc)
#pragma unroll
        for (int kc = 0; kc < 2; ++kc)
          kf[jc][kc] = *(const f16x8*)&Kb[(size_t)(jbase + jc * 16 + l15) * DH + kc * 32 + lhi * 8];
#pragma unroll
      for (int jc = 0; jc < 2; ++jc) {
        f32x4 z = {0.f, 0.f, 0.f, 0.f};
        z = mfma16(qf[0], kf[jc][0], z);
        z = mfma16(qf[1], kf[jc][1], z);
#pragma unroll
        for (int q = 0; q < 4; ++q)
          stv[bl][jc][q] = (f16)(__expf(z[q] * SCALE - mm[bl][q]) * rl[bl][q]);
      }
    }

    // deposit: 16 x ds_write_b64; granule g = bn>>2 at position g ^ (j&7)
#pragma unroll
    for (int h = 0; h < 2; ++h) {
      const int g = w * 2 + h;
#pragma unroll
      for (int jc = 0; jc < 2; ++jc)
#pragma unroll
        for (int q = 0; q < 4; ++q) {
          const int i_l = lhi * 4 + q;
          const int jl = jc * 16 + l15;
          f16x4 v = {stv[4 * h + 0][jc][q], stv[4 * h + 1][jc][q],
                     stv[4 * h + 2][jc][q], stv[4 * h + 3][jc][q]};
          *(f16x4*)&tb[(i_l * 32 + jl) * 32 + ((g ^ (jl & 7)) << 2)] = v;
        }
    }
    __syncthreads();

    // store: 8 passes; 4 lanes complete each 128B line; nt stores drain
    // under next chunk's compute (no trailing barrier needed: double buffer)
#pragma unroll
    for (int p = 0; p < 8; ++p) {
      const int i_l = p * 2 + ihalf;
      f16x8 v = *(const f16x8*)&tb[(i_l * 32 + jl_s) * 32 + (quad << 3)];
      f16x4 vl = {v[0], v[1], v[2], v[3]};
      f16x4 vh = {v[4], v[5], v[6], v[7]};
      f16x4 fa = hsw ? vh : vl;
      f16x4 fb = hsw ? vl : vh;
      f32x4 lo = {(float)fa[0], (float)fa[1], (float)fa[2], (float)fa[3]};
      f32x4 hi = {(float)fb[0], (float)fb[1], (float)fb[2], (float)fb[3]};
      float* op = pout + ((size_t)(i0 + i_l) * QLEN + jbase + jl_s) * NBN + o * 8;
      __builtin_nontemporal_store(lo, (f32x4*)op);
      __builtin_nontemporal_store(hi, (f32x4*)(op + 4));
    }
  }
}

// ---------------- launcher ----------------
extern "C" void kernel_launch(void* const* d_in, const int* in_sizes, int n_in,
                              void* d_out, int out_size, void* d_ws, size_t ws_size,
                              hipStream_t stream) {
  const float* h  = (const float*)d_in[0];
  const float* wq = (const float*)d_in[1];
  float* av   = (float*)d_out;
  float* pout = av + (size_t)QLEN * BSZ * NH * DH;

  char* ws = (char*)d_ws;
  f16* hh  = (f16*)ws;                        // 8 MiB
  f16* wh  = (f16*)(ws + (8u << 20));         // 6 MiB
  f16* Qsc = (f16*)(ws + (16u << 20));        // 8 MiB
  f16* Ksc = (f16*)(ws + (24u << 20));        // 8 MiB
  f16* Vtc = (f16*)(ws + (32u << 20));        // 8 MiB
  float* smv  = (float*)(ws + (40u << 20));
  float* srlv = (float*)(ws + (40u << 20) + (QLEN * NBN * 4));

  const int nh4 = QLEN * BSZ * DM / 4;
  const int nw4 = 3 * NH * DH * DM / 4;
  cvt_f32_f16<<<nh4 / 256, 256, 0, stream>>>(h, hh, nh4);
  cvt_f32_f16<<<nw4 / 256, 256, 0, stream>>>(wq, wh, nw4);
  qkv_gemm<<<32 * 24, 256, 0, stream>>>(hh, wh, Qsc, Ksc, Vtc);
  flash_attn<<<NBN * 16, 256, 0, stream>>>(Qsc, Ksc, Vtc, av, smv, srlv);
  write_probs<<<128 * 8, 256, 0, stream>>>(Qsc, Ksc, smv, srlv, pout);
}